// Round 9
// baseline (103.977 us; speedup 1.0000x reference)
//
#include <hip/hip_runtime.h>

typedef __bf16 bf16x8 __attribute__((ext_vector_type(8)));
typedef float f32x4 __attribute__((ext_vector_type(4)));
typedef unsigned short u16x8 __attribute__((ext_vector_type(8)));

#define MFMA16(a, b, c) __builtin_amdgcn_mfma_f32_16x16x32_bf16((a), (b), (c), 0, 0, 0)

#define INVPI 0.31830988618379067f
#define TBL_N 2048
#define TBL_SCALE 204.8f          // TBL_N / gamma_range(10)
#define TBL_STEP (10.f / 2048.f)

__device__ __forceinline__ unsigned short f2bf(float f) {
    unsigned int u = __float_as_uint(f);
    u = u + 0x7FFFu + ((u >> 16) & 1u);   // round-to-nearest-even
    return (unsigned short)(u >> 16);
}

// f(y) = -y + sin^2(y+gamma) = 0.5 - 0.5*cos(2y+2gamma) - y
__device__ __forceinline__ float feval(float y, float gp) {
    float u = fmaf(y, INVPI, gp);
    float cc = __builtin_amdgcn_cosf(u);
    return fmaf(-0.5f, cc, 0.5f - y);
}

// ---------------- K0: prep — weight converts + ODE table ----------------
// blocks   0..127 : w2 -> bf16 (8 elem/thread)
// blocks 128..143 : w3 yt-part -> bf16
// blocks 144..151 : 2048-entry ODE table
__global__ void k_prep(const float* __restrict__ w2W, const float* __restrict__ w3W,
                       const float* __restrict__ wp,
                       unsigned short* __restrict__ w2bf, unsigned short* __restrict__ w3bbf,
                       float* __restrict__ tbl) {
    int blk = blockIdx.x;
    if (blk < 128) {
        int i = (blk * 256 + threadIdx.x) * 8;
        const float4* s4 = reinterpret_cast<const float4*>(w2W + i);
        float4 a = s4[0], b = s4[1];
        u16x8 o;
        o[0] = f2bf(a.x); o[1] = f2bf(a.y); o[2] = f2bf(a.z); o[3] = f2bf(a.w);
        o[4] = f2bf(b.x); o[5] = f2bf(b.y); o[6] = f2bf(b.z); o[7] = f2bf(b.w);
        *reinterpret_cast<u16x8*>(w2bf + i) = o;
        return;
    }
    if (blk < 144) {
        int idx = ((blk - 128) * 256 + threadIdx.x) * 8;   // < 32768
        int j = idx >> 8, dk = idx & 255;
        const float4* s4 = reinterpret_cast<const float4*>(w3W + j * 1280 + 1024 + dk);
        float4 a = s4[0], b = s4[1];
        u16x8 o;
        o[0] = f2bf(a.x); o[1] = f2bf(a.y); o[2] = f2bf(a.z); o[3] = f2bf(a.w);
        o[4] = f2bf(b.x); o[5] = f2bf(b.y); o[6] = f2bf(b.z); o[7] = f2bf(b.w);
        *reinterpret_cast<u16x8*>(w3bbf + idx) = o;
        return;
    }
    {
        int gid = (blk - 144) * 256 + threadIdx.x;   // 0..2047

        float c[21];
#pragma unroll
        for (int g = 0; g < 21; ++g) c[g] = 0.f;
        {
            float wv[10];
#pragma unroll
            for (int t = 0; t < 10; ++t) wv[t] = wp[t];
            float m = wv[0];
#pragma unroll
            for (int t = 1; t < 10; ++t) m = fmaxf(m, wv[t]);
            float s = 0.f;
#pragma unroll
            for (int t = 0; t < 10; ++t) { wv[t] = __expf(wv[t] - m); s += wv[t]; }
            float inv = 1.f / s;
            const int   idxs[10]  = {0, 2, 4, 6, 8, 11, 13, 15, 17, 19};
            const float fracs[10] = {0.f, 0.22222222f, 0.44444445f, 0.6666667f, 0.8888889f,
                                     0.11111111f, 0.33333334f, 0.5555556f, 0.7777778f, 1.0f};
#pragma unroll
            for (int t = 0; t < 10; ++t) {
                float w = wv[t] * inv;
                c[idxs[t]]     += w * (1.f - fracs[t]);
                c[idxs[t] + 1] += w * fracs[t];
            }
        }

        float gamma = gid * TBL_STEP;
        float gp = gamma * INVPI;
        float y = 0.f, acc = 0.f;
#pragma unroll
        for (int st = 0; st < 20; ++st) {
            float k1 = feval(y, gp);
            float k2 = feval(fmaf(0.05f, k1, y), gp);
            float k3 = feval(fmaf(0.05f, k2, y), gp);
            float k4 = feval(fmaf(0.1f,  k3, y), gp);
            float sm = k1 + k4;
            sm = fmaf(2.f, k2, sm);
            sm = fmaf(2.f, k3, sm);
            y  = fmaf(0.1f / 6.0f, sm, y);
            acc = fmaf(c[st + 1], y, acc);
        }
        tbl[gid] = acc;
    }
}

// ---------------- K_A: per-batch feature + GEMM2-max + v ----------------
// 256 blocks (1/batch) x 512 threads (8 waves). LDS 73.7 KB -> 2 blocks/CU.
// P1: feature -> LDS (nibble-XOR swizzled bf16); yt -> GLOBAL (linear bf16).
// P2: x2 = relu(feature @ w2^T + b2); col-max over n -> xs[1024]. 2 passes.
// P3: vglob[b][j] = xs @ w3W[j,:1024] + b3[j].
__global__ void __launch_bounds__(512) k_A(
    const float* __restrict__ x, const float* __restrict__ w1W, const float* __restrict__ w1b,
    const float* __restrict__ tbl,
    const unsigned short* __restrict__ w2bf, const float* __restrict__ w2b,
    const float* __restrict__ w3W, const float* __restrict__ w3b,
    unsigned short* __restrict__ ytbf, float* __restrict__ vglob) {

    __shared__ __align__(1024) char smemA[57344];   // feature, 112 rows x 512 B
    __shared__ float tl[TBL_N];                     // 8 KB ODE table
    __shared__ float w1s[1024];                     // w1W 768 + w1b 256
    __shared__ float xs[1024];                      // col-max of x2

    const int b = blockIdx.x;
    const int t = threadIdx.x;

    // ---- stage table + w1 ----
    {
        reinterpret_cast<float4*>(tl)[t] = reinterpret_cast<const float4*>(tbl)[t];
        if (t < 192)
            reinterpret_cast<float4*>(w1s)[t] = reinterpret_cast<const float4*>(w1W)[t];
        else if (t >= 256 && t < 320)
            reinterpret_cast<float4*>(w1s + 768)[t - 256] =
                reinterpret_cast<const float4*>(w1b)[t - 256];
    }

    // ---- prefetch this thread's 7 x-rows (static indexing) ----
    float xr[7][3];
    {
        const float* xb = x + (size_t)b * 300;
        int rbase0 = t >> 5;
#pragma unroll
        for (int i = 0; i < 7; ++i) {
            int row = rbase0 + i * 16;
            if (row < 100) {
                xr[i][0] = xb[row * 3 + 0];
                xr[i][1] = xb[row * 3 + 1];
                xr[i][2] = xb[row * 3 + 2];
            } else {
                xr[i][0] = 0.f; xr[i][1] = 0.f; xr[i][2] = 0.f;
            }
        }
    }
    __syncthreads();

    // ---- P1: feature -> LDS (swizzled), yt -> global (linear, coalesced) ----
    {
        unsigned short* ytg = ytbf + (size_t)b * 25600;
#pragma unroll
        for (int i = 0; i < 7; ++i) {
            int k = t + i * 512;               // 0..3583 : 112 rows x 32 chunks
            int row = k >> 5, ch = k & 31;
            int byte = row * 512 + ((ch ^ (row & 15)) << 4);
            if (row < 100) {
                float x0 = xr[i][0], x1 = xr[i][1], x2 = xr[i][2];
                int d0 = ch * 8;
                u16x8 fv, yv;
#pragma unroll
                for (int j = 0; j < 8; ++j) {
                    int d = d0 + j;
                    float g = fmaf(x0, w1s[d * 3],
                              fmaf(x1, w1s[d * 3 + 1],
                              fmaf(x2, w1s[d * 3 + 2], w1s[768 + d])));
                    g = fmaxf(g, 0.f);
                    fv[j] = f2bf(g);
                    float tt = g * TBL_SCALE;
                    int ii = (int)tt;
                    ii = (ii > TBL_N - 2) ? (TBL_N - 2) : ii;
                    float fr = tt - (float)ii;
                    float a0 = tl[ii], a1 = tl[ii + 1];
                    yv[j] = f2bf(fmaf(fr, a1 - a0, a0));
                }
                *reinterpret_cast<u16x8*>(smemA + byte) = fv;
                *reinterpret_cast<u16x8*>(ytg + row * 256 + ch * 8) = yv;
            } else {
                *reinterpret_cast<f32x4*>(smemA + byte) = (f32x4){0.f, 0.f, 0.f, 0.f};
            }
            __builtin_amdgcn_sched_barrier(0);
        }
    }
    __syncthreads();

    const int wave = t >> 6, lane = t & 63;
    const int col16 = lane & 15, krow = lane >> 4;
    const int sw = col16 << 4;

    // ---- P2: GEMM2 + relu + col-max (2 passes x 512 cols) ----
#pragma unroll 1
    for (int q = 0; q < 2; ++q) {
        int colbase = q * 512 + wave * 64;
        const unsigned short* bp = w2bf + (size_t)(colbase + col16) * 256 + krow * 8;

        f32x4 acc[7][4];
#pragma unroll
        for (int mt = 0; mt < 7; ++mt)
#pragma unroll
            for (int ct = 0; ct < 4; ++ct) acc[mt][ct] = (f32x4){0.f, 0.f, 0.f, 0.f};

        bf16x8 Bcur[4], Bnxt[4];
#pragma unroll
        for (int ct = 0; ct < 4; ++ct)
            Bcur[ct] = *reinterpret_cast<const bf16x8*>(bp + ct * 4096);

#pragma unroll
        for (int k0 = 0; k0 < 8; ++k0) {
            int off = (k0 * 64 + krow * 16) ^ sw;
            if (k0 < 7) {
#pragma unroll
                for (int ct = 0; ct < 4; ++ct)
                    Bnxt[ct] = *reinterpret_cast<const bf16x8*>(bp + ct * 4096 + (k0 + 1) * 32);
            }
#pragma unroll
            for (int mt = 0; mt < 7; ++mt) {
                bf16x8 Af = *reinterpret_cast<const bf16x8*>(smemA + (mt * 16 + col16) * 512 + off);
#pragma unroll
                for (int ct = 0; ct < 4; ++ct)
                    acc[mt][ct] = MFMA16(Af, Bcur[ct], acc[mt][ct]);
            }
#pragma unroll
            for (int ct = 0; ct < 4; ++ct) Bcur[ct] = Bnxt[ct];
        }

        float bias[4], m[4];
#pragma unroll
        for (int ct = 0; ct < 4; ++ct) {
            bias[ct] = w2b[colbase + ct * 16 + col16];
            m[ct] = 0.f;   // true max >= 0 (relu, 100 valid rows)
        }
#pragma unroll
        for (int mt = 0; mt < 7; ++mt) {
#pragma unroll
            for (int r = 0; r < 4; ++r) {
                bool valid = (mt * 16 + krow * 4 + r) < 100;
#pragma unroll
                for (int ct = 0; ct < 4; ++ct) {
                    float v = fmaxf(acc[mt][ct][r] + bias[ct], 0.f);
                    if (valid) m[ct] = fmaxf(m[ct], v);
                }
            }
        }
#pragma unroll
        for (int ct = 0; ct < 4; ++ct) {
            m[ct] = fmaxf(m[ct], __shfl_xor(m[ct], 16));
            m[ct] = fmaxf(m[ct], __shfl_xor(m[ct], 32));
        }
        if (lane < 16) {
#pragma unroll
            for (int ct = 0; ct < 4; ++ct)
                xs[colbase + ct * 16 + lane] = m[ct];
        }
    }
    __syncthreads();

    // ---- P3: vglob[b][j] = sum_c xs[c] * w3W[j][c] + w3b[j] (wave handles 16 j) ----
    {
        int j = wave * 16;
#pragma unroll 2
        for (int jj = 0; jj < 16; ++jj, ++j) {
            const float* wr = w3W + (size_t)j * 1280;
            float s = 0.f;
#pragma unroll
            for (int cc = 0; cc < 16; ++cc) {
                int c = cc * 64 + lane;
                s = fmaf(xs[c], wr[c], s);
            }
            s += __shfl_xor(s, 1);  s += __shfl_xor(s, 2);  s += __shfl_xor(s, 4);
            s += __shfl_xor(s, 8);  s += __shfl_xor(s, 16); s += __shfl_xor(s, 32);
            if (lane == 0) vglob[(size_t)b * 128 + j] = s + w3b[j];
        }
    }
}

// ---------------- K_B: h3 = relu(v + yt @ w3b^T) ; out = h3 @ outW^T + outb ----------------
// grid 800: 32 rows per block; 4 waves, wave owns 32 cols (2 n-tiles)
__global__ void __launch_bounds__(256) k_B(
    const unsigned short* __restrict__ ytbf, const unsigned short* __restrict__ w3bbf,
    const float* __restrict__ vglob, const float* __restrict__ outW,
    const float* __restrict__ outb, float* __restrict__ out) {

    __shared__ float h3s[32][132];
    int rbase = blockIdx.x * 32;
    int wave = threadIdx.x >> 6, lane = threadIdx.x & 63;
    int col16 = lane & 15, krow = lane >> 4;

    const unsigned short* ap0 = ytbf + (size_t)(rbase + col16) * 256 + krow * 8;
    const unsigned short* ap1 = ap0 + 16 * 256;
    const unsigned short* bp0 = w3bbf + (size_t)(wave * 32 + col16) * 256 + krow * 8;
    const unsigned short* bp1 = bp0 + 16 * 256;

    f32x4 a00 = {0.f,0.f,0.f,0.f}, a01 = {0.f,0.f,0.f,0.f};
    f32x4 a10 = {0.f,0.f,0.f,0.f}, a11 = {0.f,0.f,0.f,0.f};
#pragma unroll
    for (int k0 = 0; k0 < 8; ++k0) {
        bf16x8 A0 = *reinterpret_cast<const bf16x8*>(ap0 + k0 * 32);
        bf16x8 A1 = *reinterpret_cast<const bf16x8*>(ap1 + k0 * 32);
        bf16x8 B0 = *reinterpret_cast<const bf16x8*>(bp0 + k0 * 32);
        bf16x8 B1 = *reinterpret_cast<const bf16x8*>(bp1 + k0 * 32);
        a00 = MFMA16(A0, B0, a00);
        a01 = MFMA16(A0, B1, a01);
        a10 = MFMA16(A1, B0, a10);
        a11 = MFMA16(A1, B1, a11);
    }

#pragma unroll
    for (int mt = 0; mt < 2; ++mt) {
#pragma unroll
        for (int nt = 0; nt < 2; ++nt) {
            f32x4 acc = (mt == 0) ? ((nt == 0) ? a00 : a01) : ((nt == 0) ? a10 : a11);
#pragma unroll
            for (int r = 0; r < 4; ++r) {
                int rloc  = mt * 16 + krow * 4 + r;
                int rglob = rbase + rloc;
                int bb    = rglob / 100;
                int col   = wave * 32 + nt * 16 + col16;
                float h = acc[r] + vglob[(size_t)bb * 128 + col];
                h3s[rloc][col] = fmaxf(h, 0.f);
            }
        }
    }
    __syncthreads();

    int r  = threadIdx.x >> 3;   // 0..31
    int jg = threadIdx.x & 7;    // 0..7
    float p0 = 0.f, p1 = 0.f;
#pragma unroll
    for (int tt = 0; tt < 16; ++tt) {
        int j = jg * 16 + tt;
        float h = h3s[r][j];
        p0 = fmaf(h, outW[j], p0);
        p1 = fmaf(h, outW[128 + j], p1);
    }
    p0 += __shfl_xor(p0, 1); p0 += __shfl_xor(p0, 2); p0 += __shfl_xor(p0, 4);
    p1 += __shfl_xor(p1, 1); p1 += __shfl_xor(p1, 2); p1 += __shfl_xor(p1, 4);
    if (jg == 0) {
        int rg = rbase + r;
        out[rg * 2 + 0] = p0 + outb[0];
        out[rg * 2 + 1] = p1 + outb[1];
    }
}

extern "C" void kernel_launch(void* const* d_in, const int* in_sizes, int n_in,
                              void* d_out, int out_size, void* d_ws, size_t ws_size,
                              hipStream_t stream) {
    const float* x    = (const float*)d_in[0];
    const float* w1W  = (const float*)d_in[1];
    const float* w1b  = (const float*)d_in[2];
    const float* w2W  = (const float*)d_in[3];
    const float* w2b  = (const float*)d_in[4];
    const float* w3W  = (const float*)d_in[5];
    const float* w3b  = (const float*)d_in[6];
    const float* outW = (const float*)d_in[7];
    const float* outb = (const float*)d_in[8];
    const float* wp   = (const float*)d_in[9];
    float* out = (float*)d_out;

    char* ws = (char*)d_ws;
    unsigned short* w2bf_  = (unsigned short*)(ws);             // 524,288 B
    unsigned short* w3bbf_ = (unsigned short*)(ws + 524288);    // 65,536 B
    float* tbl             = (float*)(ws + 589824);             // 8,192 B
    unsigned short* ytbf   = (unsigned short*)(ws + 598016);    // 13,107,200 B
    float* vglob           = (float*)(ws + 13705216);           // 131,072 B
    // total ws use: 13,836,288 B

    k_prep<<<152, 256, 0, stream>>>(w2W, w3W, wp, w2bf_, w3bbf_, tbl);
    k_A<<<256, 512, 0, stream>>>(x, w1W, w1b, tbl, w2bf_, w2b, w3W, w3b, ytbf, vglob);
    k_B<<<800, 256, 0, stream>>>(ytbf, w3bbf_, vglob, outW, outb, out);
}

// Round 10
// 100.583 us; speedup vs baseline: 1.0337x; 1.0337x over previous
//
#include <hip/hip_runtime.h>

typedef __bf16 bf16x8 __attribute__((ext_vector_type(8)));
typedef float f32x4 __attribute__((ext_vector_type(4)));
typedef unsigned short u16x8 __attribute__((ext_vector_type(8)));

#define MFMA16(a, b, c) __builtin_amdgcn_mfma_f32_16x16x32_bf16((a), (b), (c), 0, 0, 0)

#define INVPI 0.31830988618379067f
#define TBL_N 2048
#define TBL_SCALE 204.8f          // TBL_N / gamma_range(10)
#define TBL_STEP (10.f / 2048.f)

__device__ __forceinline__ unsigned short f2bf(float f) {
    unsigned int u = __float_as_uint(f);
    u = u + 0x7FFFu + ((u >> 16) & 1u);   // round-to-nearest-even
    return (unsigned short)(u >> 16);
}

// f(y) = -y + sin^2(y+gamma) = 0.5 - 0.5*cos(2y+2gamma) - y
__device__ __forceinline__ float feval(float y, float gp) {
    float u = fmaf(y, INVPI, gp);
    float cc = __builtin_amdgcn_cosf(u);
    return fmaf(-0.5f, cc, 0.5f - y);
}

// ---------------- K0: prep — weight converts + ODE table ----------------
// blocks   0..127 : w2 -> bf16 (8 elem/thread)
// blocks 128..143 : w3 yt-part -> bf16
// blocks 144..151 : 2048-entry ODE table
__global__ void k_prep(const float* __restrict__ w2W, const float* __restrict__ w3W,
                       const float* __restrict__ wp,
                       unsigned short* __restrict__ w2bf, unsigned short* __restrict__ w3bbf,
                       float* __restrict__ tbl) {
    int blk = blockIdx.x;
    if (blk < 128) {
        int i = (blk * 256 + threadIdx.x) * 8;
        const float4* s4 = reinterpret_cast<const float4*>(w2W + i);
        float4 a = s4[0], b = s4[1];
        u16x8 o;
        o[0] = f2bf(a.x); o[1] = f2bf(a.y); o[2] = f2bf(a.z); o[3] = f2bf(a.w);
        o[4] = f2bf(b.x); o[5] = f2bf(b.y); o[6] = f2bf(b.z); o[7] = f2bf(b.w);
        *reinterpret_cast<u16x8*>(w2bf + i) = o;
        return;
    }
    if (blk < 144) {
        int idx = ((blk - 128) * 256 + threadIdx.x) * 8;   // < 32768
        int j = idx >> 8, dk = idx & 255;
        const float4* s4 = reinterpret_cast<const float4*>(w3W + j * 1280 + 1024 + dk);
        float4 a = s4[0], b = s4[1];
        u16x8 o;
        o[0] = f2bf(a.x); o[1] = f2bf(a.y); o[2] = f2bf(a.z); o[3] = f2bf(a.w);
        o[4] = f2bf(b.x); o[5] = f2bf(b.y); o[6] = f2bf(b.z); o[7] = f2bf(b.w);
        *reinterpret_cast<u16x8*>(w3bbf + idx) = o;
        return;
    }
    {
        int gid = (blk - 144) * 256 + threadIdx.x;   // 0..2047

        float c[21];
#pragma unroll
        for (int g = 0; g < 21; ++g) c[g] = 0.f;
        {
            float wv[10];
#pragma unroll
            for (int t = 0; t < 10; ++t) wv[t] = wp[t];
            float m = wv[0];
#pragma unroll
            for (int t = 1; t < 10; ++t) m = fmaxf(m, wv[t]);
            float s = 0.f;
#pragma unroll
            for (int t = 0; t < 10; ++t) { wv[t] = __expf(wv[t] - m); s += wv[t]; }
            float inv = 1.f / s;
            const int   idxs[10]  = {0, 2, 4, 6, 8, 11, 13, 15, 17, 19};
            const float fracs[10] = {0.f, 0.22222222f, 0.44444445f, 0.6666667f, 0.8888889f,
                                     0.11111111f, 0.33333334f, 0.5555556f, 0.7777778f, 1.0f};
#pragma unroll
            for (int t = 0; t < 10; ++t) {
                float w = wv[t] * inv;
                c[idxs[t]]     += w * (1.f - fracs[t]);
                c[idxs[t] + 1] += w * fracs[t];
            }
        }

        float gamma = gid * TBL_STEP;
        float gp = gamma * INVPI;
        float y = 0.f, acc = 0.f;
#pragma unroll
        for (int st = 0; st < 20; ++st) {
            float k1 = feval(y, gp);
            float k2 = feval(fmaf(0.05f, k1, y), gp);
            float k3 = feval(fmaf(0.05f, k2, y), gp);
            float k4 = feval(fmaf(0.1f,  k3, y), gp);
            float sm = k1 + k4;
            sm = fmaf(2.f, k2, sm);
            sm = fmaf(2.f, k3, sm);
            y  = fmaf(0.1f / 6.0f, sm, y);
            acc = fmaf(c[st + 1], y, acc);
        }
        tbl[gid] = acc;
    }
}

// ---------------- K_A: per-batch feature + GEMM2-max + v ----------------
// 256 blocks (1/batch) x 512 threads (8 waves). LDS 73.7 KB.
// Register budget is 128 (2 blocks/CU LDS-fit -> 4 waves/SIMD target, unified
// VGPR+AGPR file) — P2 sized to acc[7][2] (4 passes x 32 cols/wave) to FIT.
// P1: feature -> LDS (nibble-XOR swizzled bf16); yt -> GLOBAL (linear bf16).
// P2: x2 = relu(feature @ w2^T + b2); col-max over n -> xs[1024]. 4 passes.
// P3: vglob[b][j] = xs @ w3W[j,:1024] + b3[j].
__global__ void __launch_bounds__(512) k_A(
    const float* __restrict__ x, const float* __restrict__ w1W, const float* __restrict__ w1b,
    const float* __restrict__ tbl,
    const unsigned short* __restrict__ w2bf, const float* __restrict__ w2b,
    const float* __restrict__ w3W, const float* __restrict__ w3b,
    unsigned short* __restrict__ ytbf, float* __restrict__ vglob) {

    __shared__ __align__(1024) char smemA[57344];   // feature, 112 rows x 512 B
    __shared__ float tl[TBL_N];                     // 8 KB ODE table
    __shared__ float w1s[1024];                     // w1W 768 + w1b 256
    __shared__ float xs[1024];                      // col-max of x2

    const int b = blockIdx.x;
    const int t = threadIdx.x;

    // ---- stage table + w1 ----
    {
        reinterpret_cast<float4*>(tl)[t] = reinterpret_cast<const float4*>(tbl)[t];
        if (t < 192)
            reinterpret_cast<float4*>(w1s)[t] = reinterpret_cast<const float4*>(w1W)[t];
        else if (t >= 256 && t < 320)
            reinterpret_cast<float4*>(w1s + 768)[t - 256] =
                reinterpret_cast<const float4*>(w1b)[t - 256];
    }

    // ---- prefetch this thread's 7 x-rows (static indexing) ----
    float xr[7][3];
    {
        const float* xb = x + (size_t)b * 300;
        int rbase0 = t >> 5;
#pragma unroll
        for (int i = 0; i < 7; ++i) {
            int row = rbase0 + i * 16;
            if (row < 100) {
                xr[i][0] = xb[row * 3 + 0];
                xr[i][1] = xb[row * 3 + 1];
                xr[i][2] = xb[row * 3 + 2];
            } else {
                xr[i][0] = 0.f; xr[i][1] = 0.f; xr[i][2] = 0.f;
            }
        }
    }
    __syncthreads();

    // ---- P1: feature -> LDS (swizzled), yt -> global (linear, coalesced) ----
    {
        unsigned short* ytg = ytbf + (size_t)b * 25600;
#pragma unroll
        for (int i = 0; i < 7; ++i) {
            int k = t + i * 512;               // 0..3583 : 112 rows x 32 chunks
            int row = k >> 5, ch = k & 31;
            int byte = row * 512 + ((ch ^ (row & 15)) << 4);
            if (row < 100) {
                float x0 = xr[i][0], x1 = xr[i][1], x2 = xr[i][2];
                int d0 = ch * 8;
                u16x8 fv, yv;
#pragma unroll
                for (int j = 0; j < 8; ++j) {
                    int d = d0 + j;
                    float g = fmaf(x0, w1s[d * 3],
                              fmaf(x1, w1s[d * 3 + 1],
                              fmaf(x2, w1s[d * 3 + 2], w1s[768 + d])));
                    g = fmaxf(g, 0.f);
                    fv[j] = f2bf(g);
                    float tt = g * TBL_SCALE;
                    int ii = (int)tt;
                    ii = (ii > TBL_N - 2) ? (TBL_N - 2) : ii;
                    float fr = tt - (float)ii;
                    float a0 = tl[ii], a1 = tl[ii + 1];
                    yv[j] = f2bf(fmaf(fr, a1 - a0, a0));
                }
                *reinterpret_cast<u16x8*>(smemA + byte) = fv;
                *reinterpret_cast<u16x8*>(ytg + row * 256 + ch * 8) = yv;
            } else {
                *reinterpret_cast<f32x4*>(smemA + byte) = (f32x4){0.f, 0.f, 0.f, 0.f};
            }
            __builtin_amdgcn_sched_barrier(0);
        }
    }
    __syncthreads();

    const int wave = t >> 6, lane = t & 63;
    const int col16 = lane & 15, krow = lane >> 4;
    const int sw = col16 << 4;

    // ---- P2: GEMM2 + relu + col-max (4 passes x 256 cols; wave owns 32) ----
#pragma unroll 1
    for (int q = 0; q < 4; ++q) {
        int colbase = q * 256 + wave * 32;
        const unsigned short* bp = w2bf + (size_t)(colbase + col16) * 256 + krow * 8;

        f32x4 acc[7][2];
#pragma unroll
        for (int mt = 0; mt < 7; ++mt)
#pragma unroll
            for (int ct = 0; ct < 2; ++ct) acc[mt][ct] = (f32x4){0.f, 0.f, 0.f, 0.f};

        bf16x8 Bcur[2], Bnxt[2];
#pragma unroll
        for (int ct = 0; ct < 2; ++ct)
            Bcur[ct] = *reinterpret_cast<const bf16x8*>(bp + ct * 4096);

#pragma unroll
        for (int k0 = 0; k0 < 8; ++k0) {
            int off = (k0 * 64 + krow * 16) ^ sw;
            if (k0 < 7) {
#pragma unroll
                for (int ct = 0; ct < 2; ++ct)
                    Bnxt[ct] = *reinterpret_cast<const bf16x8*>(bp + ct * 4096 + (k0 + 1) * 32);
            }
#pragma unroll
            for (int mt = 0; mt < 7; ++mt) {
                bf16x8 Af = *reinterpret_cast<const bf16x8*>(smemA + (mt * 16 + col16) * 512 + off);
#pragma unroll
                for (int ct = 0; ct < 2; ++ct)
                    acc[mt][ct] = MFMA16(Af, Bcur[ct], acc[mt][ct]);
            }
#pragma unroll
            for (int ct = 0; ct < 2; ++ct) Bcur[ct] = Bnxt[ct];
        }

        float bias[2], m[2];
#pragma unroll
        for (int ct = 0; ct < 2; ++ct) {
            bias[ct] = w2b[colbase + ct * 16 + col16];
            m[ct] = 0.f;   // true max >= 0 (relu, 100 valid rows)
        }
#pragma unroll
        for (int mt = 0; mt < 7; ++mt) {
#pragma unroll
            for (int r = 0; r < 4; ++r) {
                bool valid = (mt * 16 + krow * 4 + r) < 100;
#pragma unroll
                for (int ct = 0; ct < 2; ++ct) {
                    float v = fmaxf(acc[mt][ct][r] + bias[ct], 0.f);
                    if (valid) m[ct] = fmaxf(m[ct], v);
                }
            }
        }
#pragma unroll
        for (int ct = 0; ct < 2; ++ct) {
            m[ct] = fmaxf(m[ct], __shfl_xor(m[ct], 16));
            m[ct] = fmaxf(m[ct], __shfl_xor(m[ct], 32));
        }
        if (lane < 16) {
#pragma unroll
            for (int ct = 0; ct < 2; ++ct)
                xs[colbase + ct * 16 + lane] = m[ct];
        }
    }
    __syncthreads();

    // ---- P3: vglob[b][j] = sum_c xs[c] * w3W[j][c] + w3b[j] (wave handles 16 j) ----
    {
        int j = wave * 16;
#pragma unroll 2
        for (int jj = 0; jj < 16; ++jj, ++j) {
            const float* wr = w3W + (size_t)j * 1280;
            float s = 0.f;
#pragma unroll
            for (int cc = 0; cc < 16; ++cc) {
                int c = cc * 64 + lane;
                s = fmaf(xs[c], wr[c], s);
            }
            s += __shfl_xor(s, 1);  s += __shfl_xor(s, 2);  s += __shfl_xor(s, 4);
            s += __shfl_xor(s, 8);  s += __shfl_xor(s, 16); s += __shfl_xor(s, 32);
            if (lane == 0) vglob[(size_t)b * 128 + j] = s + w3b[j];
        }
    }
}

// ---------------- K_B: h3 = relu(v + yt @ w3b^T) ; out = h3 @ outW^T + outb ----------------
// grid 800: 32 rows per block; 4 waves, wave owns 32 cols (2 n-tiles)
__global__ void __launch_bounds__(256) k_B(
    const unsigned short* __restrict__ ytbf, const unsigned short* __restrict__ w3bbf,
    const float* __restrict__ vglob, const float* __restrict__ outW,
    const float* __restrict__ outb, float* __restrict__ out) {

    __shared__ float h3s[32][132];
    int rbase = blockIdx.x * 32;
    int wave = threadIdx.x >> 6, lane = threadIdx.x & 63;
    int col16 = lane & 15, krow = lane >> 4;

    const unsigned short* ap0 = ytbf + (size_t)(rbase + col16) * 256 + krow * 8;
    const unsigned short* ap1 = ap0 + 16 * 256;
    const unsigned short* bp0 = w3bbf + (size_t)(wave * 32 + col16) * 256 + krow * 8;
    const unsigned short* bp1 = bp0 + 16 * 256;

    f32x4 a00 = {0.f,0.f,0.f,0.f}, a01 = {0.f,0.f,0.f,0.f};
    f32x4 a10 = {0.f,0.f,0.f,0.f}, a11 = {0.f,0.f,0.f,0.f};
#pragma unroll
    for (int k0 = 0; k0 < 8; ++k0) {
        bf16x8 A0 = *reinterpret_cast<const bf16x8*>(ap0 + k0 * 32);
        bf16x8 A1 = *reinterpret_cast<const bf16x8*>(ap1 + k0 * 32);
        bf16x8 B0 = *reinterpret_cast<const bf16x8*>(bp0 + k0 * 32);
        bf16x8 B1 = *reinterpret_cast<const bf16x8*>(bp1 + k0 * 32);
        a00 = MFMA16(A0, B0, a00);
        a01 = MFMA16(A0, B1, a01);
        a10 = MFMA16(A1, B0, a10);
        a11 = MFMA16(A1, B1, a11);
    }

#pragma unroll
    for (int mt = 0; mt < 2; ++mt) {
#pragma unroll
        for (int nt = 0; nt < 2; ++nt) {
            f32x4 acc = (mt == 0) ? ((nt == 0) ? a00 : a01) : ((nt == 0) ? a10 : a11);
#pragma unroll
            for (int r = 0; r < 4; ++r) {
                int rloc  = mt * 16 + krow * 4 + r;
                int rglob = rbase + rloc;
                int bb    = rglob / 100;
                int col   = wave * 32 + nt * 16 + col16;
                float h = acc[r] + vglob[(size_t)bb * 128 + col];
                h3s[rloc][col] = fmaxf(h, 0.f);
            }
        }
    }
    __syncthreads();

    int r  = threadIdx.x >> 3;   // 0..31
    int jg = threadIdx.x & 7;    // 0..7
    float p0 = 0.f, p1 = 0.f;
#pragma unroll
    for (int tt = 0; tt < 16; ++tt) {
        int j = jg * 16 + tt;
        float h = h3s[r][j];
        p0 = fmaf(h, outW[j], p0);
        p1 = fmaf(h, outW[128 + j], p1);
    }
    p0 += __shfl_xor(p0, 1); p0 += __shfl_xor(p0, 2); p0 += __shfl_xor(p0, 4);
    p1 += __shfl_xor(p1, 1); p1 += __shfl_xor(p1, 2); p1 += __shfl_xor(p1, 4);
    if (jg == 0) {
        int rg = rbase + r;
        out[rg * 2 + 0] = p0 + outb[0];
        out[rg * 2 + 1] = p1 + outb[1];
    }
}

extern "C" void kernel_launch(void* const* d_in, const int* in_sizes, int n_in,
                              void* d_out, int out_size, void* d_ws, size_t ws_size,
                              hipStream_t stream) {
    const float* x    = (const float*)d_in[0];
    const float* w1W  = (const float*)d_in[1];
    const float* w1b  = (const float*)d_in[2];
    const float* w2W  = (const float*)d_in[3];
    const float* w2b  = (const float*)d_in[4];
    const float* w3W  = (const float*)d_in[5];
    const float* w3b  = (const float*)d_in[6];
    const float* outW = (const float*)d_in[7];
    const float* outb = (const float*)d_in[8];
    const float* wp   = (const float*)d_in[9];
    float* out = (float*)d_out;

    char* ws = (char*)d_ws;
    unsigned short* w2bf_  = (unsigned short*)(ws);             // 524,288 B
    unsigned short* w3bbf_ = (unsigned short*)(ws + 524288);    // 65,536 B
    float* tbl             = (float*)(ws + 589824);             // 8,192 B
    unsigned short* ytbf   = (unsigned short*)(ws + 598016);    // 13,107,200 B
    float* vglob           = (float*)(ws + 13705216);           // 131,072 B
    // total ws use: 13,836,288 B

    k_prep<<<152, 256, 0, stream>>>(w2W, w3W, wp, w2bf_, w3bbf_, tbl);
    k_A<<<256, 512, 0, stream>>>(x, w1W, w1b, tbl, w2bf_, w2b, w3W, w3b, ytbf, vglob);
    k_B<<<800, 256, 0, stream>>>(ytbf, w3bbf_, vglob, outW, outb, out);
}